// Round 8
// baseline (933.811 us; speedup 1.0000x reference)
//
#include <hip/hip_runtime.h>
#include <hip/hip_bf16.h>

#define TT  2048
#define NH  32
#define NKV 8
#define DD  128
#define KVB 64          // keys per LDS tile
#define THR 8.0f        // defer-max rescale threshold (T13)
#define SPLIT 17        // tiles done by the primary block of each pair

#define M_DIR  0
#define M_PART 1
#define M_WAIT 2

typedef __attribute__((ext_vector_type(8)))  short  short8;
typedef __attribute__((ext_vector_type(4)))  float  f32x4;
typedef __attribute__((ext_vector_type(16))) float  f32x16;
typedef unsigned int u32;
typedef __attribute__((ext_vector_type(4)))  u32    u32x4;

static __device__ __forceinline__ short f2bf(float x) {
  __bf16 b = (__bf16)x;                 // RNE f32->bf16
  return __builtin_bit_cast(short, b);
}
static __device__ __forceinline__ short8 cvt8(f32x4 a, f32x4 b) {
  short8 r;
  r[0]=f2bf(a[0]); r[1]=f2bf(a[1]); r[2]=f2bf(a[2]); r[3]=f2bf(a[3]);
  r[4]=f2bf(b[0]); r[5]=f2bf(b[1]); r[6]=f2bf(b[2]); r[7]=f2bf(b[3]);
  return r;
}
static __device__ __forceinline__ u32 pk2(float lo, float hi) {
  const u32 a = (u32)(unsigned short)f2bf(lo);
  const u32 b = (u32)(unsigned short)f2bf(hi);
  return a | (b << 16);
}
static __device__ __forceinline__ void gload_lds16(const short* g, short* l) {
  __builtin_amdgcn_global_load_lds(
      (const __attribute__((address_space(1))) u32*)g,
      (__attribute__((address_space(3))) u32*)l, 16, 0, 0);
}

// ---------------- pre-pass: K -> bf16 [kvh][j][d]; V -> bf16 transposed [kvh][d][j];
// also zeroes the pair-merge flags (stream order puts this before attn_fwd). --------
__global__ __launch_bounds__(256) void preconv(
    const float* __restrict__ K, const float* __restrict__ V,
    short* __restrict__ Kbf, short* __restrict__ Vtbf, u32* __restrict__ Fl)
{
  const int t = threadIdx.x;
  if (blockIdx.x >= 256) {
    if (blockIdx.x == 256) Fl[t * 16] = 0;   // one flag word per pair
    const int b  = blockIdx.x - 256;
    const int rr = (b << 6) + (t >> 2);      // rr = j*8+kvh
    const int q  = t & 3;
    const int j = rr >> 3, kvh = rr & 7;
    const float* src = K + (size_t)rr * DD + q * 32;
    short* dst = Kbf + ((size_t)kvh * TT + j) * DD + q * 32;
#pragma unroll
    for (int i = 0; i < 4; ++i) {
      f32x4 a  = *reinterpret_cast<const f32x4*>(src + i * 8);
      f32x4 bb = *reinterpret_cast<const f32x4*>(src + i * 8 + 4);
      *reinterpret_cast<short8*>(dst + i * 8) = cvt8(a, bb);
    }
  } else {
    const int kvh = blockIdx.x >> 5, jt = blockIdx.x & 31;
    __shared__ short Vl[64][136];
    const int jl = t >> 2, q = t & 3;
    const float* src = V + ((size_t)(jt * 64 + jl) * NKV + kvh) * DD + q * 32;
#pragma unroll
    for (int i = 0; i < 4; ++i) {
      f32x4 a  = *reinterpret_cast<const f32x4*>(src + i * 8);
      f32x4 bb = *reinterpret_cast<const f32x4*>(src + i * 8 + 4);
      *reinterpret_cast<short8*>(&Vl[jl][q * 32 + i * 8]) = cvt8(a, bb);
    }
    __syncthreads();
    const int d = t >> 1, jh = t & 1;
    short8 o[4];
#pragma unroll
    for (int k = 0; k < 4; ++k)
#pragma unroll
      for (int i = 0; i < 8; ++i)
        o[k][i] = Vl[jh * 32 + k * 8 + i][d];
    short* dst = Vtbf + ((size_t)kvh * DD + d) * TT + jt * 64 + jh * 32;
#pragma unroll
    for (int k = 0; k < 4; ++k)
      *reinterpret_cast<short8*>(dst + k * 8) = o[k];
  }
}

// ---------------- main attention kernel ------------------------------------------
// WORK-STEALING PAIR SPLIT for uniform per-block work (~17 tiles each):
//   pair p (kvh=p&7, w=p>>3): heavy strip q32h=63-w (Th=17..32 tiles),
//   light strip q32l=w (Tl=1..16 tiles).
//   primary  (bid=p):     tiles [0,SPLIT) of q32h  -> 17 tiles.
//   secondary(bid=p+256): light strip fully, THEN tiles [SPLIT,Th) of q32h
//                         (the stolen segment, incl. diagonal) -> 16 tiles.
//   merge: secondary writes segment partial (O',m',l') to workspace + release
//   flag (agent scope); primary spins (acquire) and combines. Grid=512 = exact
//   2-block/CU capacity (LDS 68.6KB<=80KB, launch_bounds VGPR<=128) -> whole
//   grid co-resident -> spin cannot deadlock. Flags pre-zeroed by preconv.
// Per-tile body identical to the proven round-7 kernel:
// 8 waves = 4 GQA heads x 2 key-halves; MFMA 32x32x16 swapped QK^T; per-half
// online softmax, defer-max THR=8; K/V dbuf staged by global_load_lds with
// 16B-chunk XOR swizzle; epilogue half-merge via LDS.
__global__ __launch_bounds__(512, 4) void attn_fwd(
    const float* __restrict__ Q, const short* __restrict__ Kbf,
    const short* __restrict__ Vtbf, float* __restrict__ O,
    float* __restrict__ Mo, float* __restrict__ Lo,
    float* __restrict__ Wp, float* __restrict__ Mp,
    float* __restrict__ Lp, u32* __restrict__ Fl)
{
  __shared__ __align__(16) short smem[2*KVB*DD + 2*DD*KVB];  // 64KB: Kb | Vt
  __shared__ float sx[3][2][4][32];                          // m / tmax / lsum exchange

  short (*Kb)[KVB][DD] = reinterpret_cast<short(*)[KVB][DD]>(&smem[0]);
  short (*Vt)[DD][KVB] = reinterpret_cast<short(*)[DD][KVB]>(&smem[2*KVB*DD]);

  const int bid  = blockIdx.x;
  const int role = bid >> 8;                 // 0 = primary, 1 = secondary
  const int p    = bid & 255;
  const int kvh  = p & 7;                    // kvh == XCD id under round-robin
  const int w    = p >> 3;                   // 0..31
  const int q32h = 63 - w, q32l = w;
  const int Th   = (q32h >> 1) + 1;          // 17..32
  const int Tl   = (q32l >> 1) + 1;          // 1..16
  const int seg  = Th - SPLIT;               // 0..15 stolen tiles

  const int wv   = threadIdx.x >> 6;         // 0..7
  const int headq= wv & 3;
  const int kh   = wv >> 2;                  // key half of the 64-key tile
  const int lane = threadIdx.x & 63;
  const int l31  = lane & 31;
  const int hiK  = lane >> 5;
  const int l7   = lane & 7;
  const int head = kvh * 4 + headq;
  const int p4h  = (p << 2) + headq;

  // ---- staging offsets: wave stages K rows [8wv,8wv+8), V d-rows [16wv,16wv+16)
  const int krow0 = 8 * wv + (lane >> 4);
  const int koff0 = krow0 * DD + ((lane & 15) ^ (krow0 & 7)) * 8;
  const int krow1 = krow0 + 4;
  const int koff1 = krow1 * DD + ((lane & 15) ^ (krow1 & 7)) * 8;
  const int vrow0 = 16 * wv + (lane >> 3);
  const int voff0 = vrow0 * TT + ((lane & 7) ^ (lane >> 3)) * 8;
  const int voff1 = voff0 + 8 * TT;

  const int njobs = (role == 0) ? 1 : (seg > 0 ? 2 : 1);

  for (int ji = 0; ji < njobs; ++ji) {
    int q32j, tlo, thi, mode;
    if (role == 0) { q32j = q32h; tlo = 0; thi = SPLIT; mode = seg > 0 ? M_WAIT : M_DIR; }
    else if (ji == 0) { q32j = q32l; tlo = 0; thi = Tl; mode = M_DIR; }
    else { q32j = q32h; tlo = SPLIT; thi = Th; mode = M_PART; }

    const int qbase = q32j * 32;
    const int q     = qbase + l31;           // this lane's q-column
    const int dtile = q32j >> 1;             // diagonal (masked) tile index
    const int nt    = thi - tlo;

    // ---- Q B-frags: lane holds Q[qbase+l31][ks*16 + 8*hiK + i], ks=0..7 ----
    short8 aq[8];
    {
      const float* qp = Q + ((size_t)q * NH + head) * DD + hiK * 8;
#pragma unroll
      for (int ks = 0; ks < 8; ++ks) {
        const float* pp = qp + ks * 16;
        aq[ks] = cvt8(*reinterpret_cast<const f32x4*>(pp),
                      *reinterpret_cast<const f32x4*>(pp + 4));
      }
    }

    f32x16 acc[4];
#pragma unroll
    for (int i = 0; i < 4; ++i) acc[i] = (f32x16)0.0f;
    float m = -INFINITY, tmaxh = -INFINITY, lsum = 0.0f;

    const short* kgp = Kbf + (size_t)kvh * TT * DD + (size_t)tlo * KVB * DD;
    const short* vgp = Vtbf + (size_t)kvh * DD * TT + (size_t)tlo * KVB;

    // ---- prologue: DMA first tile into buffer 0 ----
    gload_lds16(kgp + koff0, &Kb[0][8 * wv][0]);
    gload_lds16(kgp + koff1, &Kb[0][8 * wv + 4][0]);
    gload_lds16(vgp + voff0, &Vt[0][16 * wv][0]);
    gload_lds16(vgp + voff1, &Vt[0][16 * wv + 8][0]);
    kgp += (size_t)KVB * DD;
    vgp += KVB;

    for (int i = 0; i < nt; ++i) {
      const int jt  = tlo + i;
      const int buf = i & 1;

      __syncthreads();   // drains own DMA (vmcnt0); prev buffer free

      // ---- QK^T on this wave's key half ----
      f32x16 st = (f32x16)0.0f;
      const short* kr = &Kb[buf][kh * 32 + l31][0];
      __builtin_amdgcn_s_setprio(1);
#pragma unroll
      for (int ks = 0; ks < 8; ++ks) {
        const int c = ((ks << 1) | hiK) ^ l7;
        short8 kb = *reinterpret_cast<const short8*>(kr + c * 8);
        st = __builtin_amdgcn_mfma_f32_32x32x16_bf16(kb, aq[ks], st, 0, 0, 0);
      }
      __builtin_amdgcn_s_setprio(0);

      // ---- DMA next tile into buf^1 ----
      if (i + 1 < nt) {
        const int nb = buf ^ 1;
        gload_lds16(kgp + koff0, &Kb[nb][8 * wv][0]);
        gload_lds16(kgp + koff1, &Kb[nb][8 * wv + 4][0]);
        gload_lds16(vgp + voff0, &Vt[nb][16 * wv][0]);
        gload_lds16(vgp + voff1, &Vt[nb][16 * wv + 8][0]);
        kgp += (size_t)KVB * DD;
        vgp += KVB;
      }

      // ---- causal mask: only the strip's diagonal tile ----
      if (jt == dtile) {
        const int j0 = jt << 6;
#pragma unroll
        for (int r = 0; r < 16; ++r) {
          const int key = j0 + kh * 32 + (r & 3) + 8 * (r >> 2) + 4 * hiK;
          if (key > q) st[r] = -1.0e10f;
        }
      }

      // ---- half-tile max ----
      float mx = st[0];
#pragma unroll
      for (int r = 1; r < 16; ++r) mx = fmaxf(mx, st[r]);
      mx = fmaxf(mx, __shfl_xor(mx, 32, 64));
      tmaxh = fmaxf(tmaxh, mx);

      // ---- defer-max rescale ----
      if (__any(mx > m + THR)) {
        const float mn = fmaxf(m, mx);
        const float sc = __expf(m - mn);
        m = mn;
        lsum *= sc;
#pragma unroll
        for (int r = 0; r < 16; ++r) {
          const float sf = __shfl(sc, (r & 3) + 8 * (r >> 2) + 4 * hiK, 64);
          acc[0][r] *= sf; acc[1][r] *= sf; acc[2][r] *= sf; acc[3][r] *= sf;
        }
      }

      // ---- P = exp(S-m); pack to PV A-frags via lane^32 exchange ----
      float e[16];
#pragma unroll
      for (int r = 0; r < 16; ++r) e[r] = __expf(st[r] - m);
      lsum += (((e[0]+e[1])+(e[2]+e[3]))+((e[4]+e[5])+(e[6]+e[7])))
            + (((e[8]+e[9])+(e[10]+e[11]))+((e[12]+e[13])+(e[14]+e[15])));

      short8 pa[2];
#pragma unroll
      for (int h2 = 0; h2 < 2; ++h2) {
        const int b = 8 * h2;
        u32 u0 = pk2(e[b+0], e[b+1]);
        u32 u1 = pk2(e[b+2], e[b+3]);
        u32 u2 = pk2(e[b+4], e[b+5]);
        u32 u3 = pk2(e[b+6], e[b+7]);
        u32 sA = hiK ? u0 : u2;
        u32 sB = hiK ? u1 : u3;
        u32 rA = __shfl_xor(sA, 32, 64);
        u32 rB = __shfl_xor(sB, 32, 64);
        u32x4 wv4;
        wv4[0] = hiK ? rA : u0;
        wv4[1] = hiK ? rB : u1;
        wv4[2] = hiK ? u2 : rA;
        wv4[3] = hiK ? u3 : rB;
        pa[h2] = __builtin_bit_cast(short8, wv4);
      }

      // ---- P @ V over this wave's 2 key-slices ----
      __builtin_amdgcn_s_setprio(1);
#pragma unroll
      for (int dg = 0; dg < 4; ++dg) {
        const short* vr = &Vt[buf][dg * 32 + l31][0];
#pragma unroll
        for (int h2 = 0; h2 < 2; ++h2) {
          const int ksv = 2 * kh + h2;
          const int c = ((ksv << 1) | hiK) ^ l7;
          short8 vb = *reinterpret_cast<const short8*>(vr + c * 8);
          acc[dg] = __builtin_amdgcn_mfma_f32_32x32x16_bf16(pa[h2], vb, acc[dg], 0, 0, 0);
        }
      }
      __builtin_amdgcn_s_setprio(0);
    }

    // ---- epilogue: merge the two key-halves ----
    const float lw = lsum + __shfl_xor(lsum, 32, 64);
    __syncthreads();                     // all PV done; K/V LDS is dead now
    if (lane < 32) {
      sx[0][kh][headq][lane] = m;
      sx[1][kh][headq][lane] = tmaxh;
      sx[2][kh][headq][lane] = lw;
    }
    __syncthreads();
    const float mo   = sx[0][kh ^ 1][headq][l31];
    const float to   = sx[1][kh ^ 1][headq][l31];
    const float lo2  = sx[2][kh ^ 1][headq][l31];
    const float tmax = fmaxf(tmaxh, to);
    const float fsA  = __expf(m - tmax);          // own-half scale to true max
    const float ltot = lw * fsA + lo2 * __expf(mo - tmax);

    float* mbuf = reinterpret_cast<float*>(&smem[0]);
    if (kh == 1) {
#pragma unroll
      for (int r = 0; r < 16; ++r) {
        const int row = (r & 3) + 8 * (r >> 2) + 4 * hiK;
        const float sfr = __shfl(fsA, row, 64);
#pragma unroll
        for (int dg = 0; dg < 4; ++dg)
          mbuf[headq * 4096 + row * 128 + dg * 32 + l31] = acc[dg][r] * sfr;
      }
    }
    __syncthreads();
    if (kh == 0) {
      if (mode == M_WAIT) {              // wait for the stolen-segment partial
        int guard = 0;
        while (__hip_atomic_load(&Fl[p * 16], __ATOMIC_ACQUIRE,
                                 __HIP_MEMORY_SCOPE_AGENT) == 0u) {
          __builtin_amdgcn_s_sleep(2);
          if (++guard > (1 << 22)) break;   // fail-safe: never hang the queue
        }
      }
#pragma unroll
      for (int r = 0; r < 16; ++r) {
        const int row = (r & 3) + 8 * (r >> 2) + 4 * hiK;
        const float sfr = __shfl(fsA, row, 64);
        if (mode == M_DIR) {
          const size_t ob = ((size_t)(qbase + row) * NH + head) * DD + l31;
#pragma unroll
          for (int dg = 0; dg < 4; ++dg)
            O[ob + dg * 32] = acc[dg][r] * sfr + mbuf[headq * 4096 + row * 128 + dg * 32 + l31];
        } else if (mode == M_PART) {
          const size_t wb = ((size_t)p4h * 32 + row) * 128 + l31;
#pragma unroll
          for (int dg = 0; dg < 4; ++dg)
            Wp[wb + dg * 32] = acc[dg][r] * sfr + mbuf[headq * 4096 + row * 128 + dg * 32 + l31];
        } else {                          // M_WAIT: combine with partial
          const float tr = __shfl(tmax, row, 64);
          const float ms = Mp[p4h * 32 + row];
          const float M2 = fmaxf(tr, ms);
          const float a  = __expf(tr - M2);
          const float bb = __expf(ms - M2);
          const size_t ob = ((size_t)(qbase + row) * NH + head) * DD + l31;
          const size_t wb = ((size_t)p4h * 32 + row) * 128 + l31;
#pragma unroll
          for (int dg = 0; dg < 4; ++dg)
            O[ob + dg * 32] =
                (acc[dg][r] * sfr + mbuf[headq * 4096 + row * 128 + dg * 32 + l31]) * a
                + Wp[wb + dg * 32] * bb;
        }
      }
      if (lane < 32) {
        if (mode == M_DIR) {
          Mo[(size_t)q * NH + head] = tmax;
          Lo[(size_t)q * NH + head] = ltot;
        } else if (mode == M_PART) {
          Mp[p4h * 32 + lane] = tmax;
          Lp[p4h * 32 + lane] = ltot;
        } else {
          const float ms = Mp[p4h * 32 + lane];
          const float ls = Lp[p4h * 32 + lane];
          const float M2 = fmaxf(tmax, ms);
          const float a  = __expf(tmax - M2);
          const float bb = __expf(ms - M2);
          Mo[(size_t)q * NH + head] = M2;
          Lo[(size_t)q * NH + head] = ltot * a + ls * bb;
        }
      }
    }
    if (mode == M_PART) __threadfence();
    __syncthreads();                     // also protects mbuf/LDS before next job
    if (mode == M_PART && threadIdx.x == 0)
      __hip_atomic_store(&Fl[p * 16], 1u, __ATOMIC_RELEASE, __HIP_MEMORY_SCOPE_AGENT);
  }
}

extern "C" void kernel_launch(void* const* d_in, const int* in_sizes, int n_in,
                              void* d_out, int out_size, void* d_ws, size_t ws_size,
                              hipStream_t stream) {
  const float* Q = (const float*)d_in[0];
  const float* K = (const float*)d_in[1];
  const float* V = (const float*)d_in[2];
  float* O  = (float*)d_out;
  float* Mo = O + (size_t)TT * NH * DD;
  float* Lo = Mo + (size_t)TT * NH;
  short* Kbf  = (short*)d_ws;                          // 4 MB
  short* Vtbf = Kbf + (size_t)NKV * TT * DD;           // 4 MB
  float* Wp = (float*)(Vtbf + (size_t)NKV * TT * DD);  // 16 MB partial O
  float* Mp = Wp + (size_t)256 * 4 * 32 * 128;         // 128 KB
  float* Lp = Mp + 256 * 4 * 32;                       // 128 KB
  u32*   Fl = (u32*)(Lp + 256 * 4 * 32);               // 16 KB flags
  preconv<<<dim3(512), dim3(256), 0, stream>>>(K, V, Kbf, Vtbf, Fl);
  attn_fwd<<<dim3(512), dim3(512), 0, stream>>>(Q, Kbf, Vtbf, O, Mo, Lo, Wp, Mp, Lp, Fl);
}

// Round 9
// 87.822 us; speedup vs baseline: 10.6330x; 10.6330x over previous
//
#include <hip/hip_runtime.h>
#include <hip/hip_bf16.h>

#define TT  2048
#define NH  32
#define NKV 8
#define DD  128
#define KVB 96          // keys per LDS tile (3 slices x 32)
#define VROW 128        // padded V^T row: 96 data keys + 32 pad (256B, pow2 swizzle)
#define THR 8.0f        // defer-max rescale threshold (T13)

typedef __attribute__((ext_vector_type(8)))  short  short8;
typedef __attribute__((ext_vector_type(4)))  float  f32x4;
typedef __attribute__((ext_vector_type(16))) float  f32x16;
typedef unsigned int u32;
typedef __attribute__((ext_vector_type(4)))  u32    u32x4;

static __device__ __forceinline__ short f2bf(float x) {
  __bf16 b = (__bf16)x;                 // RNE f32->bf16
  return __builtin_bit_cast(short, b);
}
static __device__ __forceinline__ short8 cvt8(f32x4 a, f32x4 b) {
  short8 r;
  r[0]=f2bf(a[0]); r[1]=f2bf(a[1]); r[2]=f2bf(a[2]); r[3]=f2bf(a[3]);
  r[4]=f2bf(b[0]); r[5]=f2bf(b[1]); r[6]=f2bf(b[2]); r[7]=f2bf(b[3]);
  return r;
}
static __device__ __forceinline__ u32 pk2(float lo, float hi) {
  const u32 a = (u32)(unsigned short)f2bf(lo);
  const u32 b = (u32)(unsigned short)f2bf(hi);
  return a | (b << 16);
}
static __device__ __forceinline__ void gload_lds16(const short* g, short* l) {
  __builtin_amdgcn_global_load_lds(
      (const __attribute__((address_space(1))) u32*)g,
      (__attribute__((address_space(3))) u32*)l, 16, 0, 0);
}

// ---------------- pre-pass: K -> bf16 [kvh][j][d]; V -> bf16 transposed [kvh][d][j] ----
__global__ __launch_bounds__(256) void preconv(
    const float* __restrict__ K, const float* __restrict__ V,
    short* __restrict__ Kbf, short* __restrict__ Vtbf)
{
  const int t = threadIdx.x;
  if (blockIdx.x >= 256) {
    const int b  = blockIdx.x - 256;
    const int rr = (b << 6) + (t >> 2);      // rr = j*8+kvh
    const int q  = t & 3;
    const int j = rr >> 3, kvh = rr & 7;
    const float* src = K + (size_t)rr * DD + q * 32;
    short* dst = Kbf + ((size_t)kvh * TT + j) * DD + q * 32;
#pragma unroll
    for (int i = 0; i < 4; ++i) {
      f32x4 a  = *reinterpret_cast<const f32x4*>(src + i * 8);
      f32x4 bb = *reinterpret_cast<const f32x4*>(src + i * 8 + 4);
      *reinterpret_cast<short8*>(dst + i * 8) = cvt8(a, bb);
    }
  } else {
    const int kvh = blockIdx.x >> 5, jt = blockIdx.x & 31;
    __shared__ short Vl[64][136];
    const int jl = t >> 2, q = t & 3;
    const float* src = V + ((size_t)(jt * 64 + jl) * NKV + kvh) * DD + q * 32;
#pragma unroll
    for (int i = 0; i < 4; ++i) {
      f32x4 a  = *reinterpret_cast<const f32x4*>(src + i * 8);
      f32x4 bb = *reinterpret_cast<const f32x4*>(src + i * 8 + 4);
      *reinterpret_cast<short8*>(&Vl[jl][q * 32 + i * 8]) = cvt8(a, bb);
    }
    __syncthreads();
    const int d = t >> 1, jh = t & 1;
    short8 o[4];
#pragma unroll
    for (int k = 0; k < 4; ++k)
#pragma unroll
      for (int i = 0; i < 8; ++i)
        o[k][i] = Vl[jh * 32 + k * 8 + i][d];
    short* dst = Vtbf + ((size_t)kvh * DD + d) * TT + jt * 64 + jh * 32;
#pragma unroll
    for (int k = 0; k < 4; ++k)
      *reinterpret_cast<short8*>(dst + k * 8) = o[k];
  }
}

// ---------------- main attention kernel ------------------------------------------
// Block = one kv-head x 32 Q-rows; 12 waves (768 thr) = 4 GQA heads x 3 KEY-SLICES
// of a 96-key tile. Per-wave body identical to the proven round-7 kernel
// (32-key QK^T swapped MFMA 32x32x16, lane-local softmax, defer-max THR=8,
// lane^32 pa exchange, PV over own 2 key-slices x full 128 d).
// Occupancy: 160 unified regs/wave -> 3 waves/EU (480<=512): launch_bounds(768,3)
// caps at 170 (no spill). 12 waves/CU vs round 7's 8 (+50% latency hiding).
// LDS: Kb 2x96x256B=48K + Vt 2x128x256B=64K (96 keys + 32 pad per row so the
// pow2 XOR chunk swizzle carries over; pad staged from safe fallback addresses).
// Last tile of q32=63 covers keys 2048..2111: per-lane clamp to tile-0 source
// (finite, always causally masked -> exp->0; avoids NaN from uninit memory).
// Epilogue: 3-slice merge via sx (m/tmax/lsum) + mbuf accumulation in dead LDS.
__global__ __launch_bounds__(768, 3) void attn_fwd(
    const float* __restrict__ Q, const short* __restrict__ Kbf,
    const short* __restrict__ Vtbf, float* __restrict__ O,
    float* __restrict__ Mo, float* __restrict__ Lo)
{
  __shared__ __align__(16) short smem[2*KVB*DD + 2*DD*VROW];  // 48K + 64K = 112KB
  __shared__ float sx[3][3][4][32];                           // m/tmax/lsum per slice

  short (*Kb)[KVB][DD]   = reinterpret_cast<short(*)[KVB][DD]>(&smem[0]);
  short (*Vt)[DD][VROW]  = reinterpret_cast<short(*)[DD][VROW]>(&smem[2*KVB*DD]);

  const int bid  = blockIdx.x;
  const int kvh  = bid & (NKV - 1);          // kvh == XCD id under round-robin
  const int q32  = 63 - (bid >> 3);          // LPT: heaviest strips first
  const int wv   = threadIdx.x >> 6;         // 0..11
  const int headq= wv & 3;
  const int ks3  = wv >> 2;                  // key slice 0..2 of the 96-key tile
  const int lane = threadIdx.x & 63;
  const int l31  = lane & 31;
  const int hiK  = lane >> 5;
  const int l7   = lane & 7;
  const int head = kvh * 4 + headq;
  const int qbase = q32 * 32;
  const int q    = qbase + l31;              // this lane's q-column

  // ---- K staging: wave stages rows [8wv, 8wv+8) of the 96-row tile ----
  const int krw0  = 8 * wv + (lane >> 4);
  const int koff0 = krw0 * DD + ((lane & 15) ^ (krw0 & 7)) * 8;
  const int krw1  = krw0 + 4;
  const int koff1 = krw1 * DD + ((lane & 15) ^ (krw1 & 7)) * 8;
  // ---- V staging: 32 linear 1KB writes (rows [4w,4w+4) of Vt, 256B rows);
  //      wave wv does w in {wv, wv+12, wv+24} (w<32). Pad chunks (c>=12) pull
  //      from chunk 0 (finite garbage, never read).
  int voffA[3], vkeyA[3];
  const int nvw = (wv < 8) ? 3 : 2;
#pragma unroll
  for (int t = 0; t < 3; ++t) {
    const int w   = (wv + 12 * t) & 31;
    const int row = 4 * w + (lane >> 4);
    int c = (lane & 15) ^ (row & 7);
    if (c >= 12) c = 0;
    voffA[t] = row * TT + 8 * c;
    vkeyA[t] = 8 * c;
  }

  const short* kB = Kbf + (size_t)kvh * TT * DD;   // strip K base (also OOB fallback)
  const short* vB = Vtbf + (size_t)kvh * DD * TT;  // strip V base (also OOB fallback)

  // ---- Q B-frags: lane holds Q[qbase+l31][ks*16 + 8*hiK + i], ks=0..7 ----
  short8 aq[8];
  {
    const float* qp = Q + ((size_t)q * NH + head) * DD + hiK * 8;
#pragma unroll
    for (int ks = 0; ks < 8; ++ks) {
      const float* p = qp + ks * 16;
      aq[ks] = cvt8(*reinterpret_cast<const f32x4*>(p),
                    *reinterpret_cast<const f32x4*>(p + 4));
    }
  }

  f32x16 acc[4];
#pragma unroll
  for (int i = 0; i < 4; ++i) acc[i] = (f32x16)0.0f;
  float m = -INFINITY, tmaxh = -INFINITY, lsum = 0.0f;

  const int ntiles = (q32 + 3) / 3;   // ceil((qbase+32)/96)

  // ---- staging of tile jt2 into buffer bn (per-lane OOB clamp to tile 0) ----
  auto STAGE = [&](int bn, int jt2) {
    const int jk = 96 * jt2;
    const short* kS = kB + (size_t)jk * DD;
    const short* vS = vB + jk;
    gload_lds16(((jk + krw0 < TT) ? kS : kB) + koff0, &Kb[bn][8 * wv][0]);
    gload_lds16(((jk + krw1 < TT) ? kS : kB) + koff1, &Kb[bn][8 * wv + 4][0]);
    short* vd = &Vt[bn][0][0];
    gload_lds16(((jk + vkeyA[0] < TT) ? vS : vB) + voffA[0], vd + wv * 512);
    gload_lds16(((jk + vkeyA[1] < TT) ? vS : vB) + voffA[1], vd + (wv + 12) * 512);
    if (nvw == 3)
      gload_lds16(((jk + vkeyA[2] < TT) ? vS : vB) + voffA[2], vd + (wv + 24) * 512);
  };

  STAGE(0, 0);   // prologue

  for (int jt = 0; jt < ntiles; ++jt) {
    const int buf = jt & 1;

    __syncthreads();   // drains own DMA (vmcnt0); prev buffer free

    // ---- DMA next tile into buf^1 (lands during this tile's compute) ----
    if (jt + 1 < ntiles) STAGE(buf ^ 1, jt + 1);

    // ---- QK^T on this wave's 32-key slice: st = S^T[key][q=l31] ----
    f32x16 st = (f32x16)0.0f;
    const short* kr = &Kb[buf][ks3 * 32 + l31][0];
    __builtin_amdgcn_s_setprio(1);
#pragma unroll
    for (int ks = 0; ks < 8; ++ks) {
      const int c = ((ks << 1) | hiK) ^ l7;
      short8 kb = *reinterpret_cast<const short8*>(kr + c * 8);
      st = __builtin_amdgcn_mfma_f32_32x32x16_bf16(kb, aq[ks], st, 0, 0, 0);
    }
    __builtin_amdgcn_s_setprio(0);

    // ---- causal mask: only the last tile can cross the diagonal (or pad keys) ----
    if (jt == ntiles - 1) {
#pragma unroll
      for (int r = 0; r < 16; ++r) {
        const int key = 96 * jt + 32 * ks3 + (r & 3) + 8 * (r >> 2) + 4 * hiK;
        if (key > q) st[r] = -1.0e10f;
      }
    }

    // ---- slice max (lane-local + lane^32 merge) ----
    float mx = st[0];
#pragma unroll
    for (int r = 1; r < 16; ++r) mx = fmaxf(mx, st[r]);
    mx = fmaxf(mx, __shfl_xor(mx, 32, 64));
    tmaxh = fmaxf(tmaxh, mx);

    // ---- defer-max rescale ----
    if (__any(mx > m + THR)) {
      const float mn = fmaxf(m, mx);
      const float sc = __expf(m - mn);
      m = mn;
      lsum *= sc;
#pragma unroll
      for (int r = 0; r < 16; ++r) {
        const float sf = __shfl(sc, (r & 3) + 8 * (r >> 2) + 4 * hiK, 64);
        acc[0][r] *= sf; acc[1][r] *= sf; acc[2][r] *= sf; acc[3][r] *= sf;
      }
    }

    // ---- P = exp(S-m); pack to PV A-frags via lane^32 exchange ----
    float e[16];
#pragma unroll
    for (int r = 0; r < 16; ++r) e[r] = __expf(st[r] - m);
    lsum += (((e[0]+e[1])+(e[2]+e[3]))+((e[4]+e[5])+(e[6]+e[7])))
          + (((e[8]+e[9])+(e[10]+e[11]))+((e[12]+e[13])+(e[14]+e[15])));

    short8 pa[2];
#pragma unroll
    for (int h2 = 0; h2 < 2; ++h2) {
      const int b = 8 * h2;
      u32 u0 = pk2(e[b+0], e[b+1]);
      u32 u1 = pk2(e[b+2], e[b+3]);
      u32 u2 = pk2(e[b+4], e[b+5]);
      u32 u3 = pk2(e[b+6], e[b+7]);
      u32 sA = hiK ? u0 : u2;
      u32 sB = hiK ? u1 : u3;
      u32 rA = __shfl_xor(sA, 32, 64);
      u32 rB = __shfl_xor(sB, 32, 64);
      u32x4 w4;
      w4[0] = hiK ? rA : u0;
      w4[1] = hiK ? rB : u1;
      w4[2] = hiK ? u2 : rA;
      w4[3] = hiK ? u3 : rB;
      pa[h2] = __builtin_bit_cast(short8, w4);
    }

    // ---- P @ V over this wave's 2 key-slices x 128 d ----
    __builtin_amdgcn_s_setprio(1);
#pragma unroll
    for (int dg = 0; dg < 4; ++dg) {
      const short* vr = &Vt[buf][dg * 32 + l31][0];
#pragma unroll
      for (int h2 = 0; h2 < 2; ++h2) {
        const int ksv = 2 * ks3 + h2;
        const int c = ((ksv << 1) | hiK) ^ l7;
        short8 vb = *reinterpret_cast<const short8*>(vr + c * 8);
        acc[dg] = __builtin_amdgcn_mfma_f32_32x32x16_bf16(pa[h2], vb, acc[dg], 0, 0, 0);
      }
    }
    __builtin_amdgcn_s_setprio(0);
  }

  // ---- epilogue: merge the three key-slices ----
  const float lw = lsum + __shfl_xor(lsum, 32, 64);
  __syncthreads();                     // all PV done; K/V LDS is dead now
  if (lane < 32) {
    sx[0][ks3][headq][lane] = m;
    sx[1][ks3][headq][lane] = tmaxh;
    sx[2][ks3][headq][lane] = lw;
  }
  __syncthreads();
  const float m0 = sx[0][0][headq][l31], m1 = sx[0][1][headq][l31], m2 = sx[0][2][headq][l31];
  const float t0 = sx[1][0][headq][l31], t1 = sx[1][1][headq][l31], t2 = sx[1][2][headq][l31];
  const float l0 = sx[2][0][headq][l31], l1 = sx[2][1][headq][l31], l2 = sx[2][2][headq][l31];
  const float tmax = fmaxf(fmaxf(t0, t1), t2);
  const float fs   = __expf(m - tmax);          // own-slice scale to true max
  const float ltot = l0 * __expf(m0 - tmax) + l1 * __expf(m1 - tmax)
                   + l2 * __expf(m2 - tmax);

  float* mbuf = reinterpret_cast<float*>(&smem[0]);   // 64KB: 4 heads x 32q x 128d
  if (ks3 == 2) {
#pragma unroll
    for (int r = 0; r < 16; ++r) {
      const int row = (r & 3) + 8 * (r >> 2) + 4 * hiK;
      const float sfr = __shfl(fs, row, 64);
#pragma unroll
      for (int dg = 0; dg < 4; ++dg)
        mbuf[headq * 4096 + row * 128 + dg * 32 + l31] = acc[dg][r] * sfr;
    }
  }
  __syncthreads();
  if (ks3 == 1) {
#pragma unroll
    for (int r = 0; r < 16; ++r) {
      const int row = (r & 3) + 8 * (r >> 2) + 4 * hiK;
      const float sfr = __shfl(fs, row, 64);
#pragma unroll
      for (int dg = 0; dg < 4; ++dg)
        mbuf[headq * 4096 + row * 128 + dg * 32 + l31] += acc[dg][r] * sfr;
    }
  }
  __syncthreads();
  if (ks3 == 0) {
#pragma unroll
    for (int r = 0; r < 16; ++r) {
      const int row = (r & 3) + 8 * (r >> 2) + 4 * hiK;
      const float sfr = __shfl(fs, row, 64);
      const size_t ob = ((size_t)(qbase + row) * NH + head) * DD + l31;
#pragma unroll
      for (int dg = 0; dg < 4; ++dg)
        O[ob + dg * 32] = acc[dg][r] * sfr
                        + mbuf[headq * 4096 + row * 128 + dg * 32 + l31];
    }
    if (lane < 32) {
      Mo[(size_t)q * NH + head] = tmax;
      Lo[(size_t)q * NH + head] = ltot;
    }
  }
}

extern "C" void kernel_launch(void* const* d_in, const int* in_sizes, int n_in,
                              void* d_out, int out_size, void* d_ws, size_t ws_size,
                              hipStream_t stream) {
  const float* Q = (const float*)d_in[0];
  const float* K = (const float*)d_in[1];
  const float* V = (const float*)d_in[2];
  float* O  = (float*)d_out;
  float* Mo = O + (size_t)TT * NH * DD;
  float* Lo = Mo + (size_t)TT * NH;
  short* Kbf  = (short*)d_ws;                          // 4 MB
  short* Vtbf = Kbf + (size_t)NKV * TT * DD;           // 4 MB
  preconv<<<dim3(512), dim3(256), 0, stream>>>(K, V, Kbf, Vtbf);
  attn_fwd<<<dim3(64 * NKV), dim3(768), 0, stream>>>(Q, Kbf, Vtbf, O, Mo, Lo);
}